// Round 22
// baseline (195.908 us; speedup 1.0000x reference)
//
#include <hip/hip_runtime.h>
#include <hip/hip_bf16.h>

#define NPAPER 100000
#define NAUTH  50000
#define NROWS  150000
#define EC 200000
#define EW 100000
#define EB 100000
#define ETOT 400000
#define DIM 256
#define NH 8
#define SLOPE 0.2f
#define LN_EPS 1e-5f
#define MAXD 32            // fixed-stride CSR slots; Poisson(3) P(>=32)~1e-24

#define NT 2344            // ceil(NROWS/64)
#define PROJ_GRID 512
#define TPB 5              // tiles per proj block (512*5 >= 2344)

typedef unsigned short u16;
typedef __attribute__((ext_vector_type(8))) short s16x8;
typedef __attribute__((ext_vector_type(4))) float f32x4;

__device__ __forceinline__ float lrelu(float x){ return x >= 0.f ? x : SLOPE * x; }
__device__ __forceinline__ u16 f2b(float f){
  __hip_bfloat16 b = __float2bfloat16(f);
  return *reinterpret_cast<u16*>(&b);
}
__device__ __forceinline__ float b2f(u16 u){
  union { unsigned int i; float f; } v; v.i = ((unsigned int)u) << 16; return v.f;
}

__global__ void fill_i32(int* __restrict__ p, int v, int n){
  int i = blockIdx.x * blockDim.x + threadIdx.x;
  int stride = gridDim.x * blockDim.x;
  for (; i < n; i += stride) p[i] = v;
}

// ---- unified prep: convert W (blk 0-63), ee atomic-free (blk 64-66) ----
__global__ void prep_kernel(const float* __restrict__ fcW, const float* __restrict__ fceW,
                            const float* __restrict__ eEmb, const float* __restrict__ attn_e,
                            u16* __restrict__ Wb, float* __restrict__ eew)
{
  const int blk = blockIdx.x, tid = threadIdx.x;
  if (blk < 64){                                  // W f32 -> bf16
    int i = blk * 256 + tid;                      // 16384 float4
    float4 v = reinterpret_cast<const float4*>(fcW)[i];
    ushort4 o; o.x = f2b(v.x); o.y = f2b(v.y); o.z = f2b(v.z); o.w = f2b(v.w);
    reinterpret_cast<ushort4*>(Wb)[i] = o;
  } else {                                        // relation term, one blk/rel
    const int rel = blk - 64;
    const int c = tid;                            // output column 0..255
    float acc = 0.f;
    const float4* er4 = reinterpret_cast<const float4*>(eEmb + rel * DIM);
    const float4* wr4 = reinterpret_cast<const float4*>(fceW + (size_t)c * DIM);
    for (int k = 0; k < 64; k++){
      float4 e4 = er4[k], w4 = wr4[k];
      acc += w4.x*e4.x + w4.y*e4.y + w4.z*e4.z + w4.w*e4.w;
    }
    acc *= attn_e[c];
    #pragma unroll
    for (int m = 1; m < 32; m <<= 1) acc += __shfl_xor(acc, m, 64);
    if ((c & 31) == 0) eew[rel * NH + (c >> 5)] = acc;
  }
}

// ---- projection: W in registers, X dbuf LDS, C^T operand-swap epilogue,
//      el/er fused in epilogue via 2-step shfl over g (head == wid) ----
__global__ __launch_bounds__(512) void proj_mfma(
    const float* __restrict__ hP, const float* __restrict__ hA,
    const u16* __restrict__ Wb,
    const float* __restrict__ attn_l, const float* __restrict__ attn_r,
    u16* __restrict__ out, float* __restrict__ el, float* __restrict__ er)
{
  const int tid = threadIdx.x;
  const int l = tid & 63, wid = tid >> 6;
  const int lrow = l & 15, g = l >> 4;
  __shared__ u16 xs[2][64 * 256];                 // 2 x 32 KiB, XOR-swizzled

  const int t0 = blockIdx.x * TPB;
  if (t0 >= NT) return;
  const int nt = min(TPB, NT - t0);

  // one-time W panel load (L2-hot after prep)
  s16x8 bW0[8], bW1[8];
  {
    const u16* b0 = Wb + (size_t)(32 * wid + lrow) * DIM + g * 8;
    const u16* b1 = b0 + 16 * DIM;
    #pragma unroll
    for (int k = 0; k < 8; k++){
      bW0[k] = *reinterpret_cast<const s16x8*>(b0 + k * 32);
      bW1[k] = *reinterpret_cast<const s16x8*>(b1 + k * 32);
    }
  }
  // attn_l/attn_r at this lane's 8 columns (ni=0: 32wid+g*4.., ni=1: +16)
  float4 al0 = *reinterpret_cast<const float4*>(attn_l + 32 * wid + g * 4);
  float4 al1 = *reinterpret_cast<const float4*>(attn_l + 32 * wid + 16 + g * 4);
  float4 ar0 = *reinterpret_cast<const float4*>(attn_r + 32 * wid + g * 4);
  float4 ar1 = *reinterpret_cast<const float4*>(attn_r + 32 * wid + 16 + g * 4);

  float4 v[8];
  // prologue: stage tile 0
  #pragma unroll
  for (int it = 0; it < 8; it++){
    int i = tid + it * 512;
    int row = i >> 6, c4 = (i & 63) << 2;
    int gr = t0 * 64 + row; gr = gr < NROWS ? gr : NROWS - 1;
    const float* base = (gr < NPAPER) ? hP + (size_t)gr * DIM + c4
                                      : hA + (size_t)(gr - NPAPER) * DIM + c4;
    v[it] = *reinterpret_cast<const float4*>(base);
  }
  #pragma unroll
  for (int it = 0; it < 8; it++){
    int i = tid + it * 512;
    int row = i >> 6, c4 = (i & 63) << 2;
    ushort4 o; o.x = f2b(v[it].x); o.y = f2b(v[it].y); o.z = f2b(v[it].z); o.w = f2b(v[it].w);
    int byte = (row * 256 + c4) * 2;
    byte ^= (row & 7) << 4;
    *reinterpret_cast<ushort4*>((char*)&xs[0][0] + byte) = o;
  }
  __syncthreads();

  for (int i = 0; i < nt; i++){
    const int cur = i & 1;
    const bool more = (i + 1 < nt);
    const int r0 = (t0 + i) * 64;
    // issue next tile's global loads (hide HBM under compute)
    if (more){
      #pragma unroll
      for (int it = 0; it < 8; it++){
        int ii = tid + it * 512;
        int row = ii >> 6, c4 = (ii & 63) << 2;
        int gr = r0 + 64 + row; gr = gr < NROWS ? gr : NROWS - 1;
        const float* base = (gr < NPAPER) ? hP + (size_t)gr * DIM + c4
                                          : hA + (size_t)(gr - NPAPER) * DIM + c4;
        v[it] = *reinterpret_cast<const float4*>(base);
      }
    }
    // compute tile i from xs[cur]
    f32x4 acc[4][2];
    #pragma unroll
    for (int mi = 0; mi < 4; mi++){
      acc[mi][0] = (f32x4){0.f,0.f,0.f,0.f};
      acc[mi][1] = (f32x4){0.f,0.f,0.f,0.f};
    }
    #pragma unroll
    for (int kk = 0; kk < 8; kk++){
      s16x8 aF[4];
      #pragma unroll
      for (int mi = 0; mi < 4; mi++){
        int row = mi * 16 + lrow;
        int byte = (row * 256 + kk * 32 + g * 8) * 2;
        byte ^= (row & 7) << 4;
        aF[mi] = *reinterpret_cast<const s16x8*>((const char*)&xs[cur][0] + byte);
      }
      #pragma unroll
      for (int mi = 0; mi < 4; mi++){
        acc[mi][0] = __builtin_amdgcn_mfma_f32_16x16x32_bf16(bW0[kk], aF[mi], acc[mi][0], 0, 0, 0);
        acc[mi][1] = __builtin_amdgcn_mfma_f32_16x16x32_bf16(bW1[kk], aF[mi], acc[mi][1], 0, 0, 0);
      }
    }
    // C^T store + fused el/er (head == wid; row held by 4 lanes g=0..3)
    #pragma unroll
    for (int mi = 0; mi < 4; mi++){
      int grow = r0 + mi * 16 + lrow;
      bool ok = grow < NROWS;
      if (ok){
        #pragma unroll
        for (int ni = 0; ni < 2; ni++){
          int col = 32 * wid + ni * 16 + g * 4;
          ushort4 o;
          o.x = f2b(acc[mi][ni][0]); o.y = f2b(acc[mi][ni][1]);
          o.z = f2b(acc[mi][ni][2]); o.w = f2b(acc[mi][ni][3]);
          *reinterpret_cast<ushort4*>(out + (size_t)grow * DIM + col) = o;
        }
      }
      // lane-local 8-term dots, then reduce over g (masks 16, 32)
      float sl = acc[mi][0][0]*al0.x + acc[mi][0][1]*al0.y
               + acc[mi][0][2]*al0.z + acc[mi][0][3]*al0.w
               + acc[mi][1][0]*al1.x + acc[mi][1][1]*al1.y
               + acc[mi][1][2]*al1.z + acc[mi][1][3]*al1.w;
      float sr = acc[mi][0][0]*ar0.x + acc[mi][0][1]*ar0.y
               + acc[mi][0][2]*ar0.z + acc[mi][0][3]*ar0.w
               + acc[mi][1][0]*ar1.x + acc[mi][1][1]*ar1.y
               + acc[mi][1][2]*ar1.z + acc[mi][1][3]*ar1.w;
      sl += __shfl_xor(sl, 16, 64);  sl += __shfl_xor(sl, 32, 64);
      sr += __shfl_xor(sr, 16, 64);  sr += __shfl_xor(sr, 32, 64);
      if (ok && g == 0){
        el[(size_t)grow * NH + wid] = sl;
        er[(size_t)grow * NH + wid] = sr;
      }
    }
    // write next tile into the other buffer
    if (more){
      #pragma unroll
      for (int it = 0; it < 8; it++){
        int ii = tid + it * 512;
        int row = ii >> 6, c4 = (ii & 63) << 2;
        ushort4 o; o.x = f2b(v[it].x); o.y = f2b(v[it].y); o.z = f2b(v[it].z); o.w = f2b(v[it].w);
        int byte = (row * 256 + c4) * 2;
        byte ^= (row & 7) << 4;
        *reinterpret_cast<ushort4*>((char*)&xs[1 - cur][0] + byte) = o;
      }
    }
    __syncthreads();
  }
}

// ---- direct fixed-stride CSR scatter (cursor pre-zeroed) ----
__global__ void scatter_direct(const int* __restrict__ c_src, const int* __restrict__ c_dst,
                               const int* __restrict__ w_src, const int* __restrict__ w_dst,
                               const int* __restrict__ b_src, const int* __restrict__ b_dst,
                               int* __restrict__ cursor, int* __restrict__ eidx){
  int i = blockIdx.x * blockDim.x + threadIdx.x;
  int gd, pk;
  if (i < EC)           { gd = c_dst[i];                pk = c_src[i]; }
  else if (i < EC + EW) { gd = w_dst[i - EC];           pk = (w_src[i - EC] + NPAPER) | (1 << 20); }
  else if (i < ETOT)    { gd = NPAPER + b_dst[i - EC - EW]; pk = b_src[i - EC - EW] | (2 << 20); }
  else return;
  int pos = atomicAdd(&cursor[gd], 1);
  if (pos < MAXD) eidx[(size_t)gd * MAXD + pos] = pk;
}

// ---- batched predicated edges; half-wave per row, 8 cols/lane, 16B gathers ----
template<int K>
__device__ __forceinline__ void proc_edges(
    const int* __restrict__ erow, int base, int cnt,
    const float* __restrict__ el, float er_h,
    float ee0, float ee1, float ee2,
    const u16* __restrict__ hprojb, int sl, int h,
    float* __restrict__ a, float& zl)
{
  int pk[K]; float w[K]; s16x8 u[K];
  #pragma unroll
  for (int j = 0; j < K; j++)
    pk[j] = erow[base + (j < cnt ? j : 0)];
  #pragma unroll
  for (int j = 0; j < K; j++){
    int gs = pk[j] & 0xFFFFF, rl = pk[j] >> 20;
    u[j] = *reinterpret_cast<const s16x8*>(hprojb + (size_t)gs * DIM + sl * 8);
    float sc = el[(size_t)gs * NH + h] + er_h + (rl == 0 ? ee0 : (rl == 1 ? ee1 : ee2));
    w[j] = (j < cnt) ? __expf(lrelu(sc)) : 0.f;
  }
  #pragma unroll
  for (int j = 0; j < K; j++){
    zl += w[j];
    #pragma unroll
    for (int c = 0; c < 8; c++) a[c] += w[j] * b2f((u16)u[j][c]);
  }
}

// ---- fused: softmax-z + weighted bf16 gather + residual + LN ----
// 8 rows per 256-thr block; each 32-lane half-wave owns one row (8 cols/lane)
__global__ __launch_bounds__(256) void agg_ln_kernel(
    const int* __restrict__ counts, const int* __restrict__ eidx,
    const u16* __restrict__ hprojb,
    const float* __restrict__ el, const float* __restrict__ er,
    const float* __restrict__ eew, const float* __restrict__ gamma,
    const float* __restrict__ beta, float* __restrict__ out)
{
  const int wid = threadIdx.x >> 6, l = threadIdx.x & 63;
  const int sub = l >> 5, sl = l & 31;            // half-wave id, lane-in-half
  const int r = blockIdx.x * 8 + wid * 2 + sub;   // NROWS % 8 == 0
  const int h = sl >> 2;                          // cols sl*8..+7 are head sl>>2
  const float er_h = er[(size_t)r * NH + h];
  const float ee0 = eew[h], ee1 = eew[NH + h], ee2 = eew[2*NH + h];
  const int deg = min(counts[r], MAXD);
  const int* erow = eidx + (size_t)r * MAXD;

  float a[8];
  #pragma unroll
  for (int c = 0; c < 8; c++) a[c] = 0.f;
  float zl = 0.f;

  int base = 0;
  while (deg - base >= 8){
    proc_edges<8>(erow, base, 8, el, er_h, ee0, ee1, ee2, hprojb, sl, h, a, zl);
    base += 8;
  }
  int rem = deg - base;
  if (rem > 4)      proc_edges<8>(erow, base, rem, el, er_h, ee0, ee1, ee2, hprojb, sl, h, a, zl);
  else if (rem > 2) proc_edges<4>(erow, base, rem, el, er_h, ee0, ee1, ee2, hprojb, sl, h, a, zl);
  else if (rem > 0) proc_edges<2>(erow, base, rem, el, er_h, ee0, ee1, ee2, hprojb, sl, h, a, zl);

  float iz = (deg > 0) ? 1.f / zl : 0.f;
  s16x8 hr = *reinterpret_cast<const s16x8*>(hprojb + (size_t)r * DIM + sl * 8);
  float x[8]; float s = 0.f, q = 0.f;
  #pragma unroll
  for (int c = 0; c < 8; c++){
    x[c] = lrelu(a[c] * iz + b2f((u16)hr[c]));
    s += x[c]; q += x[c] * x[c];
  }
  // reduce within 32-lane subgroup
  #pragma unroll
  for (int m = 16; m > 0; m >>= 1){
    s += __shfl_xor(s, m, 32);
    q += __shfl_xor(q, m, 32);
  }
  float mu  = s * (1.f / DIM);
  float var = q * (1.f / DIM) - mu * mu;
  float inv = rsqrtf(var + LN_EPS);
  float4 g0  = *reinterpret_cast<const float4*>(gamma + sl * 8);
  float4 g1  = *reinterpret_cast<const float4*>(gamma + sl * 8 + 4);
  float4 bt0 = *reinterpret_cast<const float4*>(beta + sl * 8);
  float4 bt1 = *reinterpret_cast<const float4*>(beta + sl * 8 + 4);
  float4 o0, o1;
  o0.x = (x[0] - mu) * inv * g0.x + bt0.x;
  o0.y = (x[1] - mu) * inv * g0.y + bt0.y;
  o0.z = (x[2] - mu) * inv * g0.z + bt0.z;
  o0.w = (x[3] - mu) * inv * g0.w + bt0.w;
  o1.x = (x[4] - mu) * inv * g1.x + bt1.x;
  o1.y = (x[5] - mu) * inv * g1.y + bt1.y;
  o1.z = (x[6] - mu) * inv * g1.z + bt1.z;
  o1.w = (x[7] - mu) * inv * g1.w + bt1.w;
  float* op = out + (size_t)r * DIM + sl * 8;
  *reinterpret_cast<float4*>(op)     = o0;
  *reinterpret_cast<float4*>(op + 4) = o1;
}

extern "C" void kernel_launch(void* const* d_in, const int* in_sizes, int n_in,
                              void* d_out, int out_size, void* d_ws, size_t ws_size,
                              hipStream_t stream)
{
  const float* hP     = (const float*)d_in[0];
  const float* hA     = (const float*)d_in[1];
  const float* fcW    = (const float*)d_in[2];
  const float* fceW   = (const float*)d_in[3];
  const float* eEmb   = (const float*)d_in[4];
  const float* attn_l = (const float*)d_in[5];
  const float* attn_r = (const float*)d_in[6];
  const float* attn_e = (const float*)d_in[7];
  const float* gamma  = (const float*)d_in[8];
  const float* beta   = (const float*)d_in[9];
  const int* c_src  = (const int*)d_in[10];
  const int* c_dst  = (const int*)d_in[11];
  const int* w_src  = (const int*)d_in[12];
  const int* w_dst  = (const int*)d_in[13];
  const int* b_src  = (const int*)d_in[14];
  const int* b_dst  = (const int*)d_in[15];

  u16*   hprojb = (u16*)d_ws;                           // [NROWS,256] bf16
  float* el    = (float*)(hprojb + (size_t)NROWS * DIM);// [NROWS,8]
  float* er    = el    + (size_t)NROWS * NH;            // [NROWS,8]
  float* eew   = er    + (size_t)NROWS * NH;            // 24 (+pad 32)
  int*   cursor= (int*)(eew + 32);                      // [NROWS], zeroed
  int*   eidx  = cursor + NROWS;                        // [NROWS*MAXD]
  u16*   Wb    = (u16*)(eidx + (size_t)NROWS * MAXD);   // bf16 W [256*256]

  const int TB = 256;

  // zero cursor; direct scatter into fixed-stride CSR
  fill_i32<<<256, TB, 0, stream>>>(cursor, 0, NROWS);
  scatter_direct<<<(ETOT + TB - 1) / TB, TB, 0, stream>>>(c_src, c_dst, w_src, w_dst,
                                                          b_src, b_dst, cursor, eidx);

  // unified prep (convert W + atomic-free ee), projection with fused el/er
  prep_kernel<<<67, TB, 0, stream>>>(fcW, fceW, eEmb, attn_e, Wb, eew);
  proj_mfma<<<PROJ_GRID, 512, 0, stream>>>(hP, hA, Wb, attn_l, attn_r,
                                           hprojb, el, er);

  // fused softmax + aggregation + residual + LN (half-wave per row)
  agg_ln_kernel<<<NROWS / 8, TB, 0, stream>>>(cursor, eidx, hprojb,
                                              el, er, eew, gamma, beta,
                                              (float*)d_out);
}

// Round 23
// 184.982 us; speedup vs baseline: 1.0591x; 1.0591x over previous
//
#include <hip/hip_runtime.h>
#include <hip/hip_bf16.h>

#define NPAPER 100000
#define NAUTH  50000
#define NROWS  150000
#define EC 200000
#define EW 100000
#define EB 100000
#define ETOT 400000
#define DIM 256
#define NH 8
#define SLOPE 0.2f
#define LN_EPS 1e-5f
#define MAXD 32            // fixed-stride CSR slots; Poisson(3) P(>=32)~1e-24

#define NT 2344            // ceil(NROWS/64)
#define PROJ_GRID 512
#define TPB 5              // tiles per proj block (512*5 >= 2344)

typedef unsigned short u16;
typedef __attribute__((ext_vector_type(8))) short s16x8;
typedef __attribute__((ext_vector_type(4))) float f32x4;

__device__ __forceinline__ float lrelu(float x){ return x >= 0.f ? x : SLOPE * x; }
__device__ __forceinline__ u16 f2b(float f){
  __hip_bfloat16 b = __float2bfloat16(f);
  return *reinterpret_cast<u16*>(&b);
}
__device__ __forceinline__ float b2f(u16 u){
  union { unsigned int i; float f; } v; v.i = ((unsigned int)u) << 16; return v.f;
}

__global__ void fill_i32(int* __restrict__ p, int v, int n){
  int i = blockIdx.x * blockDim.x + threadIdx.x;
  int stride = gridDim.x * blockDim.x;
  for (; i < n; i += stride) p[i] = v;
}

// ---- unified prep: convert W (blk 0-63), ee atomic-free (blk 64-66) ----
__global__ void prep_kernel(const float* __restrict__ fcW, const float* __restrict__ fceW,
                            const float* __restrict__ eEmb, const float* __restrict__ attn_e,
                            u16* __restrict__ Wb, float* __restrict__ eew)
{
  const int blk = blockIdx.x, tid = threadIdx.x;
  if (blk < 64){                                  // W f32 -> bf16
    int i = blk * 256 + tid;                      // 16384 float4
    float4 v = reinterpret_cast<const float4*>(fcW)[i];
    ushort4 o; o.x = f2b(v.x); o.y = f2b(v.y); o.z = f2b(v.z); o.w = f2b(v.w);
    reinterpret_cast<ushort4*>(Wb)[i] = o;
  } else {                                        // relation term, one blk/rel
    const int rel = blk - 64;
    const int c = tid;                            // output column 0..255
    float acc = 0.f;
    const float4* er4 = reinterpret_cast<const float4*>(eEmb + rel * DIM);
    const float4* wr4 = reinterpret_cast<const float4*>(fceW + (size_t)c * DIM);
    for (int k = 0; k < 64; k++){
      float4 e4 = er4[k], w4 = wr4[k];
      acc += w4.x*e4.x + w4.y*e4.y + w4.z*e4.z + w4.w*e4.w;
    }
    acc *= attn_e[c];
    #pragma unroll
    for (int m = 1; m < 32; m <<= 1) acc += __shfl_xor(acc, m, 64);
    if ((c & 31) == 0) eew[rel * NH + (c >> 5)] = acc;
  }
}

// ---- projection: W in registers, X dbuf LDS, C^T operand-swap epilogue,
//      el/er fused in epilogue via 2-step shfl over g (head == wid) ----
__global__ __launch_bounds__(512) void proj_mfma(
    const float* __restrict__ hP, const float* __restrict__ hA,
    const u16* __restrict__ Wb,
    const float* __restrict__ attn_l, const float* __restrict__ attn_r,
    u16* __restrict__ out, float* __restrict__ el, float* __restrict__ er)
{
  const int tid = threadIdx.x;
  const int l = tid & 63, wid = tid >> 6;
  const int lrow = l & 15, g = l >> 4;
  __shared__ u16 xs[2][64 * 256];                 // 2 x 32 KiB, XOR-swizzled

  const int t0 = blockIdx.x * TPB;
  if (t0 >= NT) return;
  const int nt = min(TPB, NT - t0);

  // one-time W panel load (L2-hot after prep)
  s16x8 bW0[8], bW1[8];
  {
    const u16* b0 = Wb + (size_t)(32 * wid + lrow) * DIM + g * 8;
    const u16* b1 = b0 + 16 * DIM;
    #pragma unroll
    for (int k = 0; k < 8; k++){
      bW0[k] = *reinterpret_cast<const s16x8*>(b0 + k * 32);
      bW1[k] = *reinterpret_cast<const s16x8*>(b1 + k * 32);
    }
  }
  // attn_l/attn_r at this lane's 8 columns (ni=0: 32wid+g*4.., ni=1: +16)
  float4 al0 = *reinterpret_cast<const float4*>(attn_l + 32 * wid + g * 4);
  float4 al1 = *reinterpret_cast<const float4*>(attn_l + 32 * wid + 16 + g * 4);
  float4 ar0 = *reinterpret_cast<const float4*>(attn_r + 32 * wid + g * 4);
  float4 ar1 = *reinterpret_cast<const float4*>(attn_r + 32 * wid + 16 + g * 4);

  float4 v[8];
  // prologue: stage tile 0
  #pragma unroll
  for (int it = 0; it < 8; it++){
    int i = tid + it * 512;
    int row = i >> 6, c4 = (i & 63) << 2;
    int gr = t0 * 64 + row; gr = gr < NROWS ? gr : NROWS - 1;
    const float* base = (gr < NPAPER) ? hP + (size_t)gr * DIM + c4
                                      : hA + (size_t)(gr - NPAPER) * DIM + c4;
    v[it] = *reinterpret_cast<const float4*>(base);
  }
  #pragma unroll
  for (int it = 0; it < 8; it++){
    int i = tid + it * 512;
    int row = i >> 6, c4 = (i & 63) << 2;
    ushort4 o; o.x = f2b(v[it].x); o.y = f2b(v[it].y); o.z = f2b(v[it].z); o.w = f2b(v[it].w);
    int byte = (row * 256 + c4) * 2;
    byte ^= (row & 7) << 4;
    *reinterpret_cast<ushort4*>((char*)&xs[0][0] + byte) = o;
  }
  __syncthreads();

  for (int i = 0; i < nt; i++){
    const int cur = i & 1;
    const bool more = (i + 1 < nt);
    const int r0 = (t0 + i) * 64;
    // issue next tile's global loads (hide HBM under compute)
    if (more){
      #pragma unroll
      for (int it = 0; it < 8; it++){
        int ii = tid + it * 512;
        int row = ii >> 6, c4 = (ii & 63) << 2;
        int gr = r0 + 64 + row; gr = gr < NROWS ? gr : NROWS - 1;
        const float* base = (gr < NPAPER) ? hP + (size_t)gr * DIM + c4
                                          : hA + (size_t)(gr - NPAPER) * DIM + c4;
        v[it] = *reinterpret_cast<const float4*>(base);
      }
    }
    // compute tile i from xs[cur]
    f32x4 acc[4][2];
    #pragma unroll
    for (int mi = 0; mi < 4; mi++){
      acc[mi][0] = (f32x4){0.f,0.f,0.f,0.f};
      acc[mi][1] = (f32x4){0.f,0.f,0.f,0.f};
    }
    #pragma unroll
    for (int kk = 0; kk < 8; kk++){
      s16x8 aF[4];
      #pragma unroll
      for (int mi = 0; mi < 4; mi++){
        int row = mi * 16 + lrow;
        int byte = (row * 256 + kk * 32 + g * 8) * 2;
        byte ^= (row & 7) << 4;
        aF[mi] = *reinterpret_cast<const s16x8*>((const char*)&xs[cur][0] + byte);
      }
      #pragma unroll
      for (int mi = 0; mi < 4; mi++){
        acc[mi][0] = __builtin_amdgcn_mfma_f32_16x16x32_bf16(bW0[kk], aF[mi], acc[mi][0], 0, 0, 0);
        acc[mi][1] = __builtin_amdgcn_mfma_f32_16x16x32_bf16(bW1[kk], aF[mi], acc[mi][1], 0, 0, 0);
      }
    }
    // C^T store + fused el/er (head == wid; row held by 4 lanes g=0..3)
    #pragma unroll
    for (int mi = 0; mi < 4; mi++){
      int grow = r0 + mi * 16 + lrow;
      bool ok = grow < NROWS;
      if (ok){
        #pragma unroll
        for (int ni = 0; ni < 2; ni++){
          int col = 32 * wid + ni * 16 + g * 4;
          ushort4 o;
          o.x = f2b(acc[mi][ni][0]); o.y = f2b(acc[mi][ni][1]);
          o.z = f2b(acc[mi][ni][2]); o.w = f2b(acc[mi][ni][3]);
          *reinterpret_cast<ushort4*>(out + (size_t)grow * DIM + col) = o;
        }
      }
      // lane-local 8-term dots, then reduce over g (masks 16, 32)
      float sl = acc[mi][0][0]*al0.x + acc[mi][0][1]*al0.y
               + acc[mi][0][2]*al0.z + acc[mi][0][3]*al0.w
               + acc[mi][1][0]*al1.x + acc[mi][1][1]*al1.y
               + acc[mi][1][2]*al1.z + acc[mi][1][3]*al1.w;
      float sr = acc[mi][0][0]*ar0.x + acc[mi][0][1]*ar0.y
               + acc[mi][0][2]*ar0.z + acc[mi][0][3]*ar0.w
               + acc[mi][1][0]*ar1.x + acc[mi][1][1]*ar1.y
               + acc[mi][1][2]*ar1.z + acc[mi][1][3]*ar1.w;
      sl += __shfl_xor(sl, 16, 64);  sl += __shfl_xor(sl, 32, 64);
      sr += __shfl_xor(sr, 16, 64);  sr += __shfl_xor(sr, 32, 64);
      if (ok && g == 0){
        el[(size_t)grow * NH + wid] = sl;
        er[(size_t)grow * NH + wid] = sr;
      }
    }
    // write next tile into the other buffer
    if (more){
      #pragma unroll
      for (int it = 0; it < 8; it++){
        int ii = tid + it * 512;
        int row = ii >> 6, c4 = (ii & 63) << 2;
        ushort4 o; o.x = f2b(v[it].x); o.y = f2b(v[it].y); o.z = f2b(v[it].z); o.w = f2b(v[it].w);
        int byte = (row * 256 + c4) * 2;
        byte ^= (row & 7) << 4;
        *reinterpret_cast<ushort4*>((char*)&xs[1 - cur][0] + byte) = o;
      }
    }
    __syncthreads();
  }
}

// ---- direct fixed-stride CSR scatter (cursor pre-zeroed) ----
__global__ void scatter_direct(const int* __restrict__ c_src, const int* __restrict__ c_dst,
                               const int* __restrict__ w_src, const int* __restrict__ w_dst,
                               const int* __restrict__ b_src, const int* __restrict__ b_dst,
                               int* __restrict__ cursor, int* __restrict__ eidx){
  int i = blockIdx.x * blockDim.x + threadIdx.x;
  int gd, pk;
  if (i < EC)           { gd = c_dst[i];                pk = c_src[i]; }
  else if (i < EC + EW) { gd = w_dst[i - EC];           pk = (w_src[i - EC] + NPAPER) | (1 << 20); }
  else if (i < ETOT)    { gd = NPAPER + b_dst[i - EC - EW]; pk = b_src[i - EC - EW] | (2 << 20); }
  else return;
  int pos = atomicAdd(&cursor[gd], 1);
  if (pos < MAXD) eidx[(size_t)gd * MAXD + pos] = pk;
}

// ---- batched predicated edge processing (K independent load chains) ----
template<int K>
__device__ __forceinline__ void proc_edges(
    const int* __restrict__ erow, int base, int cnt,
    const float* __restrict__ el, float er_h,
    float ee0, float ee1, float ee2,
    const u16* __restrict__ hprojb, int l, int h,
    float& ax, float& ay, float& az, float& aw, float& zl)
{
  int pk[K]; float w[K]; ushort4 u[K];
  #pragma unroll
  for (int j = 0; j < K; j++)
    pk[j] = erow[base + (j < cnt ? j : 0)];
  #pragma unroll
  for (int j = 0; j < K; j++){
    int gs = pk[j] & 0xFFFFF, rl = pk[j] >> 20;
    u[j] = *reinterpret_cast<const ushort4*>(hprojb + (size_t)gs * DIM + l * 4);
    float sc = el[(size_t)gs * NH + h] + er_h + (rl == 0 ? ee0 : (rl == 1 ? ee1 : ee2));
    w[j] = (j < cnt) ? __expf(lrelu(sc)) : 0.f;
  }
  #pragma unroll
  for (int j = 0; j < K; j++){
    zl += w[j];
    ax += w[j] * b2f(u[j].x); ay += w[j] * b2f(u[j].y);
    az += w[j] * b2f(u[j].z); aw += w[j] * b2f(u[j].w);
  }
}

// ---- fused: softmax-z + weighted bf16 gather + residual + LN; one wave/row ----
__global__ __launch_bounds__(256) void agg_ln_kernel(
    const int* __restrict__ counts, const int* __restrict__ eidx,
    const u16* __restrict__ hprojb,
    const float* __restrict__ el, const float* __restrict__ er,
    const float* __restrict__ eew, const float* __restrict__ gamma,
    const float* __restrict__ beta, float* __restrict__ out)
{
  const int wid = threadIdx.x >> 6, l = threadIdx.x & 63;
  const int r = blockIdx.x * 4 + wid;
  if (r >= NROWS) return;
  const int h = l >> 3;
  const float er_h = er[(size_t)r * NH + h];
  const float ee0 = eew[h], ee1 = eew[NH + h], ee2 = eew[2*NH + h];
  const int deg = min(counts[r], MAXD);
  const int* erow = eidx + (size_t)r * MAXD;

  float ax = 0.f, ay = 0.f, az = 0.f, aw = 0.f, zl = 0.f;
  int base = 0;
  while (deg - base >= 8){
    proc_edges<8>(erow, base, 8, el, er_h, ee0, ee1, ee2, hprojb, l, h, ax, ay, az, aw, zl);
    base += 8;
  }
  int rem = deg - base;
  if (rem > 4)      proc_edges<8>(erow, base, rem, el, er_h, ee0, ee1, ee2, hprojb, l, h, ax, ay, az, aw, zl);
  else if (rem > 2) proc_edges<4>(erow, base, rem, el, er_h, ee0, ee1, ee2, hprojb, l, h, ax, ay, az, aw, zl);
  else if (rem > 0) proc_edges<2>(erow, base, rem, el, er_h, ee0, ee1, ee2, hprojb, l, h, ax, ay, az, aw, zl);

  float iz = (deg > 0) ? 1.f / zl : 0.f;
  ushort4 hr = *reinterpret_cast<const ushort4*>(hprojb + (size_t)r * DIM + l * 4);
  float x0 = lrelu(ax * iz + b2f(hr.x));
  float x1 = lrelu(ay * iz + b2f(hr.y));
  float x2 = lrelu(az * iz + b2f(hr.z));
  float x3 = lrelu(aw * iz + b2f(hr.w));
  float s = x0 + x1 + x2 + x3;
  float q = x0*x0 + x1*x1 + x2*x2 + x3*x3;
  #pragma unroll
  for (int m = 32; m > 0; m >>= 1){
    s += __shfl_xor(s, m, 64);
    q += __shfl_xor(q, m, 64);
  }
  float mu  = s * (1.f / DIM);
  float var = q * (1.f / DIM) - mu * mu;
  float inv = rsqrtf(var + LN_EPS);
  float4 g  = *reinterpret_cast<const float4*>(gamma + l * 4);
  float4 bt = *reinterpret_cast<const float4*>(beta + l * 4);
  float4 o;
  o.x = (x0 - mu) * inv * g.x + bt.x;
  o.y = (x1 - mu) * inv * g.y + bt.y;
  o.z = (x2 - mu) * inv * g.z + bt.z;
  o.w = (x3 - mu) * inv * g.w + bt.w;
  *reinterpret_cast<float4*>(out + (size_t)r * DIM + l * 4) = o;
}

extern "C" void kernel_launch(void* const* d_in, const int* in_sizes, int n_in,
                              void* d_out, int out_size, void* d_ws, size_t ws_size,
                              hipStream_t stream)
{
  const float* hP     = (const float*)d_in[0];
  const float* hA     = (const float*)d_in[1];
  const float* fcW    = (const float*)d_in[2];
  const float* fceW   = (const float*)d_in[3];
  const float* eEmb   = (const float*)d_in[4];
  const float* attn_l = (const float*)d_in[5];
  const float* attn_r = (const float*)d_in[6];
  const float* attn_e = (const float*)d_in[7];
  const float* gamma  = (const float*)d_in[8];
  const float* beta   = (const float*)d_in[9];
  const int* c_src  = (const int*)d_in[10];
  const int* c_dst  = (const int*)d_in[11];
  const int* w_src  = (const int*)d_in[12];
  const int* w_dst  = (const int*)d_in[13];
  const int* b_src  = (const int*)d_in[14];
  const int* b_dst  = (const int*)d_in[15];

  u16*   hprojb = (u16*)d_ws;                           // [NROWS,256] bf16
  float* el    = (float*)(hprojb + (size_t)NROWS * DIM);// [NROWS,8]
  float* er    = el    + (size_t)NROWS * NH;            // [NROWS,8]
  float* eew   = er    + (size_t)NROWS * NH;            // 24 (+pad 32)
  int*   cursor= (int*)(eew + 32);                      // [NROWS], zeroed
  int*   eidx  = cursor + NROWS;                        // [NROWS*MAXD]
  u16*   Wb    = (u16*)(eidx + (size_t)NROWS * MAXD);   // bf16 W [256*256]

  const int TB = 256;

  // zero cursor; direct scatter into fixed-stride CSR
  fill_i32<<<256, TB, 0, stream>>>(cursor, 0, NROWS);
  scatter_direct<<<(ETOT + TB - 1) / TB, TB, 0, stream>>>(c_src, c_dst, w_src, w_dst,
                                                          b_src, b_dst, cursor, eidx);

  // unified prep (convert W + atomic-free ee), projection with fused el/er
  prep_kernel<<<67, TB, 0, stream>>>(fcW, fceW, eEmb, attn_e, Wb, eew);
  proj_mfma<<<PROJ_GRID, 512, 0, stream>>>(hP, hA, Wb, attn_l, attn_r,
                                           hprojb, el, er);

  // fused softmax + aggregation + residual + LN
  agg_ln_kernel<<<NROWS / 4, TB, 0, stream>>>(cursor, eidx, hprojb,
                                              el, er, eew, gamma, beta,
                                              (float*)d_out);
}